// Round 1
// baseline (833.695 us; speedup 1.0000x reference)
//
#include <hip/hip_runtime.h>
#include <hip/hip_bf16.h>

#define NBLK 32
#define CAP  1024
#define DK   256
#define DV   256
#define HID  768
#define NQ   8192

#define NEG_INF (-__builtin_inff())

typedef __bf16 bfv8 __attribute__((ext_vector_type(8)));
typedef float  f32x4 __attribute__((ext_vector_type(4)));

__device__ __forceinline__ unsigned short f2bf(float x){
  unsigned int u = __float_as_uint(x);
  u += 0x7FFFu + ((u >> 16) & 1u);   // round-to-nearest-even
  return (unsigned short)(u >> 16);
}

// ---------------- element-wise cast fp32 -> bf16 ----------------
__global__ void k_cast(const float* __restrict__ src, unsigned short* __restrict__ dst, int n){
  int i = (blockIdx.x * blockDim.x + threadIdx.x) * 4;
  if (i >= n) return;
  float4 v = *reinterpret_cast<const float4*>(src + i);
  union { unsigned short s[4]; uint2 u; } o;
  o.s[0] = f2bf(v.x); o.s[1] = f2bf(v.y); o.s[2] = f2bf(v.z); o.s[3] = f2bf(v.w);
  *reinterpret_cast<uint2*>(dst + i) = o.u;
}

// ------------- transpose + cast: src[z][R][C] f32 -> dst[z][C][R] bf16 -------------
__global__ void k_transpose_cast(const float* __restrict__ src, unsigned short* __restrict__ dst,
                                 int R, int C){
  __shared__ float tile[64][65];
  int r0 = blockIdx.x * 64, c0 = blockIdx.y * 64;
  size_t base = (size_t)blockIdx.z * (size_t)R * (size_t)C;
  int t = threadIdx.x;
  #pragma unroll
  for (int it = 0; it < 16; ++it){
    int idx = it * 256 + t;
    int ri = idx >> 6, ci = idx & 63;
    tile[ri][ci] = src[base + (size_t)(r0 + ri) * C + (c0 + ci)];
  }
  __syncthreads();
  #pragma unroll
  for (int it = 0; it < 16; ++it){
    int idx = it * 256 + t;
    int ci = idx >> 6, ri = idx & 63;
    dst[base + (size_t)(c0 + ci) * R + (r0 + ri)] = f2bf(tile[ri][ci]);
  }
}

// ------------- q-projection GEMM + bias + LayerNorm + (1/16) + bf16 store -------------
__global__ __launch_bounds__(256, 2)
void k_qproj(const float* __restrict__ hs, const unsigned short* __restrict__ WkT,
             const float* __restrict__ bk, const float* __restrict__ lnw,
             const float* __restrict__ lnb, unsigned short* __restrict__ qb){
  __shared__ unsigned short Asm[64][72];    // hidden tile  [64 rows][64 k] bf16 (pad 8)
  __shared__ unsigned short Bsm[256][72];   // WkT tile     [256 col][64 k] bf16 (pad 8)
  int r0 = blockIdx.x * 64;
  int t = threadIdx.x, wid = t >> 6, lane = t & 63, g = lane >> 4, fr = lane & 15;
  f32x4 acc[16];
  #pragma unroll
  for (int i = 0; i < 16; ++i) acc[i] = f32x4{0.f, 0.f, 0.f, 0.f};
  for (int k0 = 0; k0 < HID; k0 += 64){
    __syncthreads();
    #pragma unroll
    for (int it = 0; it < 4; ++it){
      int idx = it * 256 + t;
      int row = idx >> 4, c4 = (idx & 15) * 4;
      float4 v = *reinterpret_cast<const float4*>(hs + (size_t)(r0 + row) * HID + k0 + c4);
      union { unsigned short s[4]; uint2 u; } o;
      o.s[0]=f2bf(v.x); o.s[1]=f2bf(v.y); o.s[2]=f2bf(v.z); o.s[3]=f2bf(v.w);
      *reinterpret_cast<uint2*>(&Asm[row][c4]) = o.u;
    }
    #pragma unroll
    for (int it = 0; it < 8; ++it){
      int idx = it * 256 + t;
      int row = idx >> 3, kc = (idx & 7) * 8;
      *reinterpret_cast<int4*>(&Bsm[row][kc]) =
          *reinterpret_cast<const int4*>(WkT + (size_t)row * HID + k0 + kc);
    }
    __syncthreads();
    #pragma unroll
    for (int kk = 0; kk < 2; ++kk){
      bfv8 a = *reinterpret_cast<const bfv8*>(&Asm[wid * 16 + fr][kk * 32 + g * 8]);
      #pragma unroll
      for (int dt = 0; dt < 16; ++dt){
        bfv8 b = *reinterpret_cast<const bfv8*>(&Bsm[dt * 16 + fr][kk * 32 + g * 8]);
        acc[dt] = __builtin_amdgcn_mfma_f32_16x16x32_bf16(a, b, acc[dt], 0, 0, 0);
      }
    }
  }
  // bias + LN stats (per output row; row lives in one 16-lane group, reg r)
  float sum[4] = {0,0,0,0}, sq[4] = {0,0,0,0};
  #pragma unroll
  for (int dt = 0; dt < 16; ++dt){
    float bkv = bk[dt * 16 + fr];
    #pragma unroll
    for (int r = 0; r < 4; ++r){
      float v = acc[dt][r] + bkv;
      acc[dt][r] = v;
      sum[r] += v; sq[r] += v * v;
    }
  }
  #pragma unroll
  for (int r = 0; r < 4; ++r){
    float s = sum[r], q = sq[r];
    s += __shfl_xor(s, 1);  q += __shfl_xor(q, 1);
    s += __shfl_xor(s, 2);  q += __shfl_xor(q, 2);
    s += __shfl_xor(s, 4);  q += __shfl_xor(q, 4);
    s += __shfl_xor(s, 8);  q += __shfl_xor(q, 8);
    sum[r] = s; sq[r] = q;
  }
  #pragma unroll
  for (int dt = 0; dt < 16; ++dt){
    float w = lnw[dt * 16 + fr], bb = lnb[dt * 16 + fr];
    #pragma unroll
    for (int r = 0; r < 4; ++r){
      float mu  = sum[r] * (1.f / 256.f);
      float var = sq[r] * (1.f / 256.f) - mu * mu;
      float rs  = rsqrtf(var + 1e-5f);
      float v   = ((acc[dt][r] - mu) * rs * w + bb) * 0.0625f;  // fold 1/sqrt(256)
      qb[(size_t)(r0 + wid * 16 + 4 * g + r) * DK + dt * 16 + fr] = f2bf(v);
    }
  }
}

// ------------- flash attention over memory blocks (per-block softmax, sum over blocks) -------------
__global__ __launch_bounds__(256, 2)
void k_attn(const unsigned short* __restrict__ qb, const unsigned short* __restrict__ Kb,
            const unsigned short* __restrict__ VTb, const int* __restrict__ usage,
            float* __restrict__ retr){
  __shared__ unsigned short Ksm[64][264];    // K tile  [64 kv][256 d]  (+8 pad)
  __shared__ unsigned short Vsm[256][72];    // V^T tile [256 d][64 kv] (+8 pad)
  __shared__ unsigned short Psm[4][16][72];  // per-wave P [16 q][64 kv] (+8 pad)
  int q0 = blockIdx.x * 64;
  int bg = blockIdx.y;                       // block-group 0..3
  int t = threadIdx.x, wid = t >> 6, lane = t & 63, g = lane >> 4, fr = lane & 15;
  // hoist Q fragments (rows = this wave's 16 queries)
  bfv8 qf[8];
  #pragma unroll
  for (int kk = 0; kk < 8; ++kk)
    qf[kk] = *reinterpret_cast<const bfv8*>(qb + (size_t)(q0 + wid * 16 + fr) * DK + kk * 32 + g * 8);
  f32x4 ACC[16];
  #pragma unroll
  for (int i = 0; i < 16; ++i) ACC[i] = f32x4{0.f,0.f,0.f,0.f};

  for (int bi = 0; bi < 8; ++bi){
    int b = bg + bi * 4;                     // interleaved block assignment
    int u = usage[b];
    f32x4 O[16];
    #pragma unroll
    for (int i = 0; i < 16; ++i) O[i] = f32x4{0.f,0.f,0.f,0.f};
    float m[4] = {NEG_INF, NEG_INF, NEG_INF, NEG_INF};
    float l[4] = {0.f, 0.f, 0.f, 0.f};
    int nt = (u + 63) >> 6;
    const unsigned short* Kbase = Kb  + (size_t)b * CAP * DK;
    const unsigned short* Vbase = VTb + (size_t)b * DV * CAP;

    for (int tt = 0; tt < nt; ++tt){
      int c0 = tt * 64;
      __syncthreads();                       // protect previous tile's LDS reads
      #pragma unroll
      for (int it = 0; it < 8; ++it){        // stage K tile
        int idx = it * 256 + t;
        int row = idx >> 5, ch = (idx & 31) * 8;
        *reinterpret_cast<int4*>(&Ksm[row][ch]) =
            *reinterpret_cast<const int4*>(Kbase + (size_t)(c0 + row) * DK + ch);
      }
      #pragma unroll
      for (int it = 0; it < 8; ++it){        // stage V^T tile
        int idx = it * 256 + t;
        int row = idx >> 3, ch = (idx & 7) * 8;
        *reinterpret_cast<int4*>(&Vsm[row][ch]) =
            *reinterpret_cast<const int4*>(Vbase + (size_t)row * CAP + c0 + ch);
      }
      __syncthreads();
      // S = Q K^T (scaled q)
      f32x4 s[4];
      #pragma unroll
      for (int j = 0; j < 4; ++j){
        s[j] = f32x4{0.f,0.f,0.f,0.f};
        #pragma unroll
        for (int kk = 0; kk < 8; ++kk){
          bfv8 kf = *reinterpret_cast<const bfv8*>(&Ksm[j * 16 + fr][kk * 32 + g * 8]);
          s[j] = __builtin_amdgcn_mfma_f32_16x16x32_bf16(qf[kk], kf, s[j], 0, 0, 0);
        }
      }
      // mask invalid kv, per-row tile max
      float tm[4] = {NEG_INF, NEG_INF, NEG_INF, NEG_INF};
      #pragma unroll
      for (int j = 0; j < 4; ++j){
        bool bad = (c0 + j * 16 + fr) >= u;
        #pragma unroll
        for (int r = 0; r < 4; ++r){
          float v = bad ? NEG_INF : s[j][r];
          s[j][r] = v;
          tm[r] = fmaxf(tm[r], v);
        }
      }
      #pragma unroll
      for (int r = 0; r < 4; ++r){
        float v = tm[r];
        v = fmaxf(v, __shfl_xor(v, 1));
        v = fmaxf(v, __shfl_xor(v, 2));
        v = fmaxf(v, __shfl_xor(v, 4));
        v = fmaxf(v, __shfl_xor(v, 8));
        tm[r] = v;
      }
      float sc[4], rs[4];
      #pragma unroll
      for (int r = 0; r < 4; ++r){
        float mn = fmaxf(m[r], tm[r]);
        sc[r] = __expf(m[r] - mn);           // first tile: exp(-inf) = 0
        m[r] = mn;
        rs[r] = 0.f;
      }
      #pragma unroll
      for (int j = 0; j < 4; ++j)
        #pragma unroll
        for (int r = 0; r < 4; ++r){
          float p = __expf(s[j][r] - m[r]);  // masked: exp(-inf) = 0
          s[j][r] = p;
          rs[r] += p;
        }
      #pragma unroll
      for (int r = 0; r < 4; ++r){
        float v = rs[r];
        v += __shfl_xor(v, 1);
        v += __shfl_xor(v, 2);
        v += __shfl_xor(v, 4);
        v += __shfl_xor(v, 8);
        l[r] = l[r] * sc[r] + v;
      }
      #pragma unroll
      for (int dt = 0; dt < 16; ++dt)
        #pragma unroll
        for (int r = 0; r < 4; ++r)
          O[dt][r] *= sc[r];
      // P -> per-wave LDS (C/D layout -> A-operand layout via LDS roundtrip)
      #pragma unroll
      for (int j = 0; j < 4; ++j)
        #pragma unroll
        for (int r = 0; r < 4; ++r)
          Psm[wid][4 * g + r][j * 16 + fr] = f2bf(s[j][r]);
      asm volatile("s_waitcnt lgkmcnt(0)" ::: "memory");  // cross-lane P write->read, same wave
      bfv8 pa[2];
      #pragma unroll
      for (int ks = 0; ks < 2; ++ks)
        pa[ks] = *reinterpret_cast<const bfv8*>(&Psm[wid][fr][ks * 32 + g * 8]);
      #pragma unroll
      for (int dt = 0; dt < 16; ++dt){
        #pragma unroll
        for (int ks = 0; ks < 2; ++ks){
          bfv8 vf = *reinterpret_cast<const bfv8*>(&Vsm[dt * 16 + fr][ks * 32 + g * 8]);
          O[dt] = __builtin_amdgcn_mfma_f32_16x16x32_bf16(pa[ks], vf, O[dt], 0, 0, 0);
        }
      }
    }
    // fold this block: ACC += O / l   (u >= 1 so l > 0)
    float inv[4];
    #pragma unroll
    for (int r = 0; r < 4; ++r) inv[r] = 1.f / l[r];
    #pragma unroll
    for (int dt = 0; dt < 16; ++dt)
      #pragma unroll
      for (int r = 0; r < 4; ++r)
        ACC[dt][r] += O[dt][r] * inv[r];
  }
  #pragma unroll
  for (int dt = 0; dt < 16; ++dt)
    #pragma unroll
    for (int r = 0; r < 4; ++r)
      atomicAdd(&retr[(size_t)(q0 + wid * 16 + 4 * g + r) * DV + dt * 16 + fr], ACC[dt][r]);
}

// ------------- output projection: retrieved @ Wo + bo -------------
__global__ __launch_bounds__(256, 2)
void k_outproj(const float* __restrict__ retr, const unsigned short* __restrict__ WoT,
               const float* __restrict__ bo, float* __restrict__ out){
  __shared__ unsigned short Asm[64][72];     // retrieved tile [64 rows][64 k] bf16
  __shared__ unsigned short Bsm[256][72];    // WoT tile       [256 col][64 k] bf16
  int r0 = blockIdx.x * 64, c0 = blockIdx.y * 256;
  int t = threadIdx.x, wid = t >> 6, lane = t & 63, g = lane >> 4, fr = lane & 15;
  f32x4 acc[16];
  #pragma unroll
  for (int i = 0; i < 16; ++i) acc[i] = f32x4{0.f,0.f,0.f,0.f};
  for (int k0 = 0; k0 < DV; k0 += 64){
    __syncthreads();
    #pragma unroll
    for (int it = 0; it < 4; ++it){
      int idx = it * 256 + t;
      int row = idx >> 4, c4 = (idx & 15) * 4;
      float4 v = *reinterpret_cast<const float4*>(retr + (size_t)(r0 + row) * DV + k0 + c4);
      union { unsigned short s[4]; uint2 u; } o;
      o.s[0]=f2bf(v.x); o.s[1]=f2bf(v.y); o.s[2]=f2bf(v.z); o.s[3]=f2bf(v.w);
      *reinterpret_cast<uint2*>(&Asm[row][c4]) = o.u;
    }
    #pragma unroll
    for (int it = 0; it < 8; ++it){
      int idx = it * 256 + t;
      int row = idx >> 3, kc = (idx & 7) * 8;
      *reinterpret_cast<int4*>(&Bsm[row][kc]) =
          *reinterpret_cast<const int4*>(WoT + (size_t)(c0 + row) * DV + k0 + kc);
    }
    __syncthreads();
    #pragma unroll
    for (int kk = 0; kk < 2; ++kk){
      bfv8 a = *reinterpret_cast<const bfv8*>(&Asm[wid * 16 + fr][kk * 32 + g * 8]);
      #pragma unroll
      for (int dt = 0; dt < 16; ++dt){
        bfv8 b = *reinterpret_cast<const bfv8*>(&Bsm[dt * 16 + fr][kk * 32 + g * 8]);
        acc[dt] = __builtin_amdgcn_mfma_f32_16x16x32_bf16(a, b, acc[dt], 0, 0, 0);
      }
    }
  }
  #pragma unroll
  for (int dt = 0; dt < 16; ++dt){
    #pragma unroll
    for (int r = 0; r < 4; ++r){
      int row = r0 + wid * 16 + 4 * g + r;
      int col = c0 + dt * 16 + fr;
      out[(size_t)row * HID + col] = acc[dt][r] + bo[col];
    }
  }
}

extern "C" void kernel_launch(void* const* d_in, const int* in_sizes, int n_in,
                              void* d_out, int out_size, void* d_ws, size_t ws_size,
                              hipStream_t stream){
  const float* hs  = (const float*)d_in[0];
  const float* Wk  = (const float*)d_in[1];
  const float* bk  = (const float*)d_in[2];
  const float* lnw = (const float*)d_in[3];
  const float* lnb = (const float*)d_in[4];
  const float* MK  = (const float*)d_in[5];
  const float* MV  = (const float*)d_in[6];
  const float* Wo  = (const float*)d_in[7];
  const float* bo  = (const float*)d_in[8];
  const int*   bu  = (const int*)d_in[9];
  float* out = (float*)d_out;

  char* ws = (char*)d_ws;
  unsigned short* qb  = (unsigned short*)(ws);                      //  4 MB: q bf16 [8192][256]
  unsigned short* Kb  = (unsigned short*)(ws + (size_t)( 4u<<20));  // 16 MB: K bf16 [32][1024][256]
  unsigned short* VTb = (unsigned short*)(ws + (size_t)(20u<<20));  // 16 MB: V^T bf16 [32][256][1024]
  unsigned short* WkT = (unsigned short*)(ws + (size_t)(36u<<20));  // 384 KB
  unsigned short* WoT = (unsigned short*)(ws + (size_t)(37u<<20));  // 384 KB
  float*          retr= (float*)(ws + (size_t)(38u<<20));           //  8 MB: retrieved f32

  k_cast<<<dim3(8192), dim3(256), 0, stream>>>(MK, Kb, NBLK * CAP * DK);
  k_transpose_cast<<<dim3(16, 4, 32), dim3(256), 0, stream>>>(MV, VTb, CAP, DV);
  k_transpose_cast<<<dim3(12, 4, 1),  dim3(256), 0, stream>>>(Wk, WkT, HID, DK);
  k_transpose_cast<<<dim3(4, 12, 1),  dim3(256), 0, stream>>>(Wo, WoT, DV, HID);
  k_qproj<<<dim3(128), dim3(256), 0, stream>>>(hs, WkT, bk, lnw, lnb, qb);
  hipMemsetAsync(retr, 0, (size_t)NQ * DV * sizeof(float), stream);
  k_attn<<<dim3(128, 4), dim3(256), 0, stream>>>(qb, Kb, VTb, bu, retr);
  k_outproj<<<dim3(128, 3), dim3(256), 0, stream>>>(retr, WoT, bo, out);
}

// Round 5
// 613.089 us; speedup vs baseline: 1.3598x; 1.3598x over previous
//
#include <hip/hip_runtime.h>
#include <hip/hip_bf16.h>

#define NBLK 32
#define CAP  1024
#define DK   256
#define DV   256
#define HID  768
#define NQ   8192

#define NEG_INF (-__builtin_inff())

typedef __bf16 bfv8 __attribute__((ext_vector_type(8)));
typedef float  f32x4  __attribute__((ext_vector_type(4)));
typedef float  f32x16 __attribute__((ext_vector_type(16)));

__device__ __forceinline__ unsigned short f2bf(float x){
  unsigned int u = __float_as_uint(x);
  u += 0x7FFFu + ((u >> 16) & 1u);   // round-to-nearest-even
  return (unsigned short)(u >> 16);
}

#define GLOAD16(gp, lp) __builtin_amdgcn_global_load_lds( \
    (const __attribute__((address_space(1))) unsigned int*)(gp), \
    (__attribute__((address_space(3))) unsigned int*)(lp), 16, 0, 0)

// ---------------- element-wise cast fp32 -> bf16 ----------------
__global__ void k_cast(const float* __restrict__ src, unsigned short* __restrict__ dst, int n){
  int i = (blockIdx.x * blockDim.x + threadIdx.x) * 4;
  if (i >= n) return;
  float4 v = *reinterpret_cast<const float4*>(src + i);
  union { unsigned short s[4]; uint2 u; } o;
  o.s[0] = f2bf(v.x); o.s[1] = f2bf(v.y); o.s[2] = f2bf(v.z); o.s[3] = f2bf(v.w);
  *reinterpret_cast<uint2*>(dst + i) = o.u;
}

// ------------- transpose + cast: src[z][R][C] f32 -> dst[z][C][R] bf16 -------------
__global__ void k_transpose_cast(const float* __restrict__ src, unsigned short* __restrict__ dst,
                                 int R, int C){
  __shared__ float tile[64][65];
  int r0 = blockIdx.x * 64, c0 = blockIdx.y * 64;
  size_t base = (size_t)blockIdx.z * (size_t)R * (size_t)C;
  int t = threadIdx.x;
  #pragma unroll
  for (int it = 0; it < 16; ++it){
    int idx = it * 256 + t;
    int ri = idx >> 6, ci = idx & 63;
    tile[ri][ci] = src[base + (size_t)(r0 + ri) * C + (c0 + ci)];
  }
  __syncthreads();
  #pragma unroll
  for (int it = 0; it < 16; ++it){
    int idx = it * 256 + t;
    int ci = idx >> 6, ri = idx & 63;
    dst[base + (size_t)(c0 + ci) * R + (r0 + ri)] = f2bf(tile[ri][ci]);
  }
}

// ------------- q-projection: one wave per 16 rows, B streamed from L2 -------------
__global__ __launch_bounds__(64)
void k_qproj2(const float* __restrict__ hs, const unsigned short* __restrict__ WkT,
              const float* __restrict__ bk, const float* __restrict__ lnw,
              const float* __restrict__ lnb, unsigned short* __restrict__ qb){
  int l = threadIdx.x, fr = l & 15, g = l >> 4;
  int r0 = blockIdx.x * 16;
  f32x4 acc[16];
  #pragma unroll
  for (int i = 0; i < 16; ++i) acc[i] = f32x4{0.f,0.f,0.f,0.f};
  for (int k0 = 0; k0 < HID; k0 += 32){
    const float* ap = hs + (size_t)(r0 + fr) * HID + k0 + g * 8;
    float4 a0 = *reinterpret_cast<const float4*>(ap);
    float4 a1 = *reinterpret_cast<const float4*>(ap + 4);
    union { unsigned short u[8]; bfv8 v; } A;
    A.u[0]=f2bf(a0.x); A.u[1]=f2bf(a0.y); A.u[2]=f2bf(a0.z); A.u[3]=f2bf(a0.w);
    A.u[4]=f2bf(a1.x); A.u[5]=f2bf(a1.y); A.u[6]=f2bf(a1.z); A.u[7]=f2bf(a1.w);
    #pragma unroll
    for (int dt = 0; dt < 16; ++dt){
      bfv8 b = *reinterpret_cast<const bfv8*>(WkT + (size_t)(dt*16 + fr) * HID + k0 + g*8);
      acc[dt] = __builtin_amdgcn_mfma_f32_16x16x32_bf16(A.v, b, acc[dt], 0, 0, 0);
    }
  }
  float sum[4] = {0,0,0,0}, sq[4] = {0,0,0,0};
  #pragma unroll
  for (int dt = 0; dt < 16; ++dt){
    float bkv = bk[dt*16 + fr];
    #pragma unroll
    for (int r = 0; r < 4; ++r){
      float v = acc[dt][r] + bkv;
      acc[dt][r] = v;
      sum[r] += v; sq[r] += v * v;
    }
  }
  #pragma unroll
  for (int r = 0; r < 4; ++r){
    float s = sum[r], q = sq[r];
    s += __shfl_xor(s, 1);  q += __shfl_xor(q, 1);
    s += __shfl_xor(s, 2);  q += __shfl_xor(q, 2);
    s += __shfl_xor(s, 4);  q += __shfl_xor(q, 4);
    s += __shfl_xor(s, 8);  q += __shfl_xor(q, 8);
    sum[r] = s; sq[r] = q;
  }
  #pragma unroll
  for (int dt = 0; dt < 16; ++dt){
    float w = lnw[dt*16 + fr], bb = lnb[dt*16 + fr];
    #pragma unroll
    for (int r = 0; r < 4; ++r){
      float mu  = sum[r] * (1.f/256.f);
      float var = sq[r] * (1.f/256.f) - mu * mu;
      float rsq = rsqrtf(var + 1e-5f);
      float v   = ((acc[dt][r] - mu) * rsq * w + bb) * 0.0625f;   // fold 1/sqrt(256)
      qb[(size_t)(r0 + 4*g + r) * DK + dt*16 + fr] = f2bf(v);
    }
  }
}

// ------------- flash attention: 32x32 MFMA, swapped QK^T, gload_lds dbuf -------------
// FOLD==0: per-block results RMW'd (non-atomic) into f32 partial[bg][NQ][DV]
// FOLD==1: per-block results atomicAdd'd into f32 retr[NQ][DV] (dst)
template<int FOLD>
__global__ __launch_bounds__(256, 2)
void k_attn3(const unsigned short* __restrict__ qb, const unsigned short* __restrict__ Kb,
             const unsigned short* __restrict__ VTb, const int* __restrict__ usage,
             float* __restrict__ dst){
  __shared__ unsigned short Ksm[2][32*256];   // [buf][kv 32][d 256] swizzled units
  __shared__ unsigned short Vsm[2][128*64];   // [buf][prow 128][64 shorts] (row-pairs of V^T[256][32])
  __shared__ unsigned short Pt[4][32*40];     // per-wave P[32 q][32 kv] (+8 pad)
  const int t = threadIdx.x, w = t >> 6, l = t & 63;
  const int lq = l & 31, hi = l >> 5;
  const int qtile = blockIdx.x, bg = blockIdx.y;
  const int qrow = qtile * 128 + w * 32 + lq;

  // Q fragments: A/B 32x32x16 layout: row/col = lane&31, k = (lane>>5)*8 + e
  bfv8 qf[16];
  #pragma unroll
  for (int ks = 0; ks < 16; ++ks)
    qf[ks] = *reinterpret_cast<const bfv8*>(qb + (size_t)qrow * DK + ks*16 + hi*8);

  // staging per-lane constants
  int krow[4], koff[4], voff[4];
  #pragma unroll
  for (int i = 0; i < 4; ++i){
    int idx = w*4 + i;
    int row = idx*2 + hi;                 // K tile row (kv), this lane
    krow[i] = row;
    koff[i] = ((l & 31) ^ (row & 7)) * 8; // swizzled source unit -> element offset
    int prow = idx*8 + (l >> 3);          // V packed row
    int n = (l & 7) ^ (prow & 7);         // nominal unit this lane must fetch
    int dv = 2*prow + (n >> 2);
    voff[i] = dv * CAP + (n & 3) * 8;     // + c0 at stage time
  }
  int bs[4], us[4], nts[4];
  #pragma unroll
  for (int i = 0; i < 4; ++i){ bs[i] = bg + i*8; us[i] = usage[bs[i]]; nts[i] = (us[i] + 31) >> 5; }

  unsigned short* Pw = &Pt[w][0];

  auto STAGE = [&](int buf, int b, int tt){
    const unsigned short* Kbase = Kb  + (size_t)b * CAP * DK;
    const unsigned short* Vbase = VTb + (size_t)b * DV * CAP;
    int c0 = tt * 32;
    #pragma unroll
    for (int i = 0; i < 4; ++i){
      GLOAD16(Kbase + (size_t)(c0 + krow[i]) * DK + koff[i], &Ksm[buf][(w*4 + i) * 512]);
      GLOAD16(Vbase + voff[i] + c0,                          &Vsm[buf][(w*4 + i) * 512]);
    }
  };

  int cur = 0;
  STAGE(0, bs[0], 0);
  __syncthreads();

  #pragma unroll 1
  for (int i = 0; i < 4; ++i){
    const int u = us[i], nt = nts[i];
    float m = NEG_INF, lsum = 0.f;
    f32x16 O[8];
    #pragma unroll
    for (int r = 0; r < 8; ++r)
      #pragma unroll
      for (int j = 0; j < 16; ++j) O[r][j] = 0.f;

    #pragma unroll 1
    for (int tt = 0; tt < nt; ++tt){
      bool isLast = (i == 3) && (tt == nt - 1);
      if (!isLast){
        int ni  = (tt + 1 < nt) ? i : i + 1;
        int ntt = (tt + 1 < nt) ? tt + 1 : 0;
        STAGE(cur ^ 1, bs[ni & 3], ntt);
      }
      int c0 = tt * 32;
      // ---- S^T = K * Q^T : D[row=kv][col=q]
      f32x16 s;
      #pragma unroll
      for (int j = 0; j < 16; ++j) s[j] = 0.f;
      const unsigned short* Kc = &Ksm[cur][0];
      #pragma unroll
      for (int ks = 0; ks < 16; ++ks){
        bfv8 kf = *reinterpret_cast<const bfv8*>(Kc + lq*DK + (((2*ks + hi) ^ (lq & 7)) * 8));
        s = __builtin_amdgcn_mfma_f32_32x32x16_bf16(kf, qf[ks], s, 0, 0, 0);
      }
      // ---- mask + per-row (q) max; rows of S^T per reg: kv = (r&3)+8*(r>>2)+4*hi
      float tm = NEG_INF;
      #pragma unroll
      for (int r = 0; r < 16; ++r){
        int kv = (r & 3) + 8*(r >> 2) + 4*hi;
        if (c0 + kv >= u) s[r] = NEG_INF;
        tm = fmaxf(tm, s[r]);
      }
      tm = fmaxf(tm, __shfl_xor(tm, 32));
      float mn = fmaxf(m, tm);
      if (!__all(tm - m <= 8.f)){          // defer-max (T13)
        float sc = __expf(m - mn);
        m = mn; lsum *= sc;
        #pragma unroll
        for (int r = 0; r < 8; ++r) O[r] *= sc;
      }
      float rs = 0.f;
      #pragma unroll
      for (int r = 0; r < 16; ++r){
        float e = __expf(s[r] - m);
        s[r] = e; rs += e;
      }
      rs += __shfl_xor(rs, 32);
      lsum += rs;
      // ---- P -> per-wave LDS (pack 4 consecutive kv as b64)
      #pragma unroll
      for (int blk = 0; blk < 4; ++blk){
        unsigned int w0 = (unsigned int)f2bf(s[4*blk])   | ((unsigned int)f2bf(s[4*blk+1]) << 16);
        unsigned int w1 = (unsigned int)f2bf(s[4*blk+2]) | ((unsigned int)f2bf(s[4*blk+3]) << 16);
        *reinterpret_cast<uint2*>(Pw + lq*40 + blk*8 + hi*4) = uint2{w0, w1};
      }
      asm volatile("s_waitcnt lgkmcnt(0)" ::: "memory");
      __builtin_amdgcn_sched_barrier(0);
      bfv8 pa0 = *reinterpret_cast<const bfv8*>(Pw + lq*40 + hi*8);
      bfv8 pa1 = *reinterpret_cast<const bfv8*>(Pw + lq*40 + 16 + hi*8);
      // ---- O^T += V^T * P : D[row=dv][col=q]
      const unsigned short* Vc = &Vsm[cur][0];
      #pragma unroll
      for (int rt = 0; rt < 8; ++rt){
        int dv = rt*32 + lq;
        int prow = dv >> 1;
        int a4 = (dv & 1) * 4;
        int n0 = (a4 + hi)     ^ (prow & 7);
        int n1 = (a4 + 2 + hi) ^ (prow & 7);
        bfv8 v0 = *reinterpret_cast<const bfv8*>(Vc + prow*64 + n0*8);
        bfv8 v1 = *reinterpret_cast<const bfv8*>(Vc + prow*64 + n1*8);
        O[rt] = __builtin_amdgcn_mfma_f32_32x32x16_bf16(v0, pa0, O[rt], 0, 0, 0);
        O[rt] = __builtin_amdgcn_mfma_f32_32x32x16_bf16(v1, pa1, O[rt], 0, 0, 0);
      }
      __syncthreads();
      cur ^= 1;
    }
    // ---- fold this block: rows dv = rt*32 + blk*8 + hi*4 + j, col q = lq
    float inv = 1.f / lsum;
    if constexpr (FOLD == 0){
      float* pb = dst + ((size_t)bg * NQ + qrow) * DV;   // private f32 partial slice
      #pragma unroll
      for (int rt = 0; rt < 8; ++rt){
        #pragma unroll
        for (int blk = 0; blk < 4; ++blk){
          int dv0 = rt*32 + blk*8 + hi*4;
          float4* p4 = reinterpret_cast<float4*>(pb + dv0);
          float4 vv;
          vv.x = O[rt][blk*4 + 0] * inv;
          vv.y = O[rt][blk*4 + 1] * inv;
          vv.z = O[rt][blk*4 + 2] * inv;
          vv.w = O[rt][blk*4 + 3] * inv;
          if (i > 0){
            float4 o = *p4;
            vv.x += o.x; vv.y += o.y; vv.z += o.z; vv.w += o.w;
          }
          *p4 = vv;
        }
      }
    } else {
      float* pb = dst + (size_t)qrow * DV;               // shared retr, atomic
      #pragma unroll
      for (int rt = 0; rt < 8; ++rt){
        #pragma unroll
        for (int blk = 0; blk < 4; ++blk){
          int dv0 = rt*32 + blk*8 + hi*4;
          #pragma unroll
          for (int j = 0; j < 4; ++j)
            atomicAdd(pb + dv0 + j, O[rt][blk*4 + j] * inv);
        }
      }
    }
  }
}

// ------------- reduce 8 f32 partials -> retr f32 -------------
__global__ void k_reduce(const float* __restrict__ partial, float* __restrict__ retr){
  int i = (blockIdx.x * 256 + threadIdx.x) * 4;
  float4 acc = {0.f, 0.f, 0.f, 0.f};
  #pragma unroll
  for (int bg = 0; bg < 8; ++bg){
    float4 v = *reinterpret_cast<const float4*>(partial + (size_t)bg * NQ * DV + i);
    acc.x += v.x; acc.y += v.y; acc.z += v.z; acc.w += v.w;
  }
  *reinterpret_cast<float4*>(retr + i) = acc;
}

// ------------- output projection: one wave per 16 rows x 256 cols -------------
__global__ __launch_bounds__(64)
void k_outproj3(const float* __restrict__ retr, const unsigned short* __restrict__ WoT,
                const float* __restrict__ bo, float* __restrict__ out){
  int l = threadIdx.x, fr = l & 15, g = l >> 4;
  int r0 = blockIdx.x * 16, c0 = blockIdx.y * 256;
  f32x4 acc[16];
  #pragma unroll
  for (int i = 0; i < 16; ++i) acc[i] = f32x4{0.f,0.f,0.f,0.f};
  #pragma unroll
  for (int k0 = 0; k0 < DV; k0 += 32){
    const float* ap = retr + (size_t)(r0 + fr) * DV + k0 + g*8;
    float4 a0 = *reinterpret_cast<const float4*>(ap);
    float4 a1 = *reinterpret_cast<const float4*>(ap + 4);
    union { unsigned short u[8]; bfv8 v; } A;
    A.u[0]=f2bf(a0.x); A.u[1]=f2bf(a0.y); A.u[2]=f2bf(a0.z); A.u[3]=f2bf(a0.w);
    A.u[4]=f2bf(a1.x); A.u[5]=f2bf(a1.y); A.u[6]=f2bf(a1.z); A.u[7]=f2bf(a1.w);
    #pragma unroll
    for (int dt = 0; dt < 16; ++dt){
      bfv8 b = *reinterpret_cast<const bfv8*>(WoT + (size_t)(c0 + dt*16 + fr) * DV + k0 + g*8);
      acc[dt] = __builtin_amdgcn_mfma_f32_16x16x32_bf16(A.v, b, acc[dt], 0, 0, 0);
    }
  }
  #pragma unroll
  for (int dt = 0; dt < 16; ++dt){
    float bv = bo[c0 + dt*16 + fr];
    #pragma unroll
    for (int r = 0; r < 4; ++r)
      out[(size_t)(r0 + 4*g + r) * HID + c0 + dt*16 + fr] = acc[dt][r] + bv;
  }
}

extern "C" void kernel_launch(void* const* d_in, const int* in_sizes, int n_in,
                              void* d_out, int out_size, void* d_ws, size_t ws_size,
                              hipStream_t stream){
  const float* hs  = (const float*)d_in[0];
  const float* Wk  = (const float*)d_in[1];
  const float* bk  = (const float*)d_in[2];
  const float* lnw = (const float*)d_in[3];
  const float* lnb = (const float*)d_in[4];
  const float* MK  = (const float*)d_in[5];
  const float* MV  = (const float*)d_in[6];
  const float* Wo  = (const float*)d_in[7];
  const float* bo  = (const float*)d_in[8];
  const int*   bu  = (const int*)d_in[9];
  float* out = (float*)d_out;

  char* ws = (char*)d_ws;
  unsigned short* qb   = (unsigned short*)(ws);                        //  4 MB  q bf16 [8192][256]
  unsigned short* Kb   = (unsigned short*)(ws + (size_t)( 4u<<20));    // 16 MB  K bf16 [32][1024][256]
  unsigned short* VTb  = (unsigned short*)(ws + (size_t)(20u<<20));    // 16 MB  V^T bf16 [32][256][1024]
  unsigned short* WkT  = (unsigned short*)(ws + (size_t)(36u<<20));    // 384 KB [256][768]
  unsigned short* WoT  = (unsigned short*)(ws + (size_t)(36u<<20) + 393216); // 384 KB [768][256]
  float*          retr = (float*)(ws + (size_t)(37u<<20));             //  8 MB  retrieved f32 [8192][256]
  float*        partial = (float*)(ws + (size_t)(45u<<20));            // 64 MB  [8][8192][256] f32 (opt)

  const bool big_ws = ws_size >= ((size_t)110 << 20);  // host-constant -> graph-safe

  k_cast<<<dim3(8192), dim3(256), 0, stream>>>(MK, Kb, NBLK * CAP * DK);
  k_transpose_cast<<<dim3(16, 4, 32), dim3(256), 0, stream>>>(MV, VTb, CAP, DV);
  k_transpose_cast<<<dim3(12, 4, 1),  dim3(256), 0, stream>>>(Wk, WkT, HID, DK);
  k_transpose_cast<<<dim3(4, 12, 1),  dim3(256), 0, stream>>>(Wo, WoT, DV, HID);
  k_qproj2<<<dim3(512), dim3(64), 0, stream>>>(hs, WkT, bk, lnw, lnb, qb);

  if (big_ws){
    k_attn3<0><<<dim3(64, 8), dim3(256), 0, stream>>>(qb, Kb, VTb, bu, partial);
    k_reduce<<<dim3(2048), dim3(256), 0, stream>>>(partial, retr);
  } else {
    hipMemsetAsync(retr, 0, (size_t)NQ * DV * sizeof(float), stream);
    k_attn3<1><<<dim3(64, 8), dim3(256), 0, stream>>>(qb, Kb, VTb, bu, retr);
  }
  k_outproj3<<<dim3(512, 3), dim3(64), 0, stream>>>(retr, WoT, bo, out);
}